// Round 9
// baseline (140.666 us; speedup 1.0000x reference)
//
#include <hip/hip_runtime.h>
#include <stdint.h>

#define B_ 32
#define T_ 32
#define NPIX 784
#define NFRM 1024
#define EPSV 1e-3f

typedef __attribute__((ext_vector_type(8))) _Float16 half8v;
typedef __attribute__((ext_vector_type(4))) float float4v;

// ---- LDS map (bytes) ----
// act region [0, 75456)       : fp16 acts, 6 cb * 12576 B; chunk = (cb, pixel) 16B
// zero page  [75456, 75472)
// x region   [75472, 78608)   : raw frame fp32 (784*4)
#define CB_STRIDE 12576
#define ZERO_OFF  75456
#define X_OFF     75472
#define LDS_TOT   78608
#define WPACK     43008              // bytes per conv weight pack

__device__ __forceinline__ unsigned short f2h(float f) {
    union { _Float16 h; unsigned short u; } cv; cv.h = (_Float16)f; return cv.u;
}

// ---------------------------------------------------------------------------
// Kernel 0: pack w2/w3 as fp16 in MFMA-B fragment order [s][q][co][j].
// k = s*32 + q*8 + j = tap*48 + cin ; k >= 432 zero-padded.
// ---------------------------------------------------------------------------
__global__ __launch_bounds__(256) void pack_weights(
    const float* __restrict__ w2, const float* __restrict__ w3,
    unsigned short* __restrict__ out)
{
    int idx = blockIdx.x * 256 + threadIdx.x;     // 0 .. 43007
    int conv = idx / 21504;
    int r = idx - conv * 21504;
    const float* w = conv ? w3 : w2;
    int s  = r / 1536;
    int r2 = r - s * 1536;
    int q  = r2 / 384;
    int r3 = r2 - q * 384;
    int co = r3 >> 3, j = r3 & 7;
    int k  = s * 32 + q * 8 + j;
    unsigned short v = 0;
    if (k < 432) v = f2h(w[k * 48 + co]);
    out[idx] = v;
}

// ---------------------------------------------------------------------------
// Fused conv1 + conv2 + conv3 (fp16 MFMA) + ReLU + avgpool + BN1.
// One block = one frame; 1024 threads = 16 waves; wave w owns tiles tt=w+16*mt.
// Register model (R5/R6): unified VGPR file, 16-wave block needs total<=128;
// acc=48 so arch <= ~80 via two-half conv1, no persistent per-s arrays,
// s-bitmask validity, transient bias loads.
// R7 BUG FIX: tap = k/48 via (k*11)>>9 was WRONG at k=280 (gave 6, true 5)
// -> negative kc -> read below act region. Use (k*1366)>>16: exact for k<481
// (ceil(65536/48)=1366; error 0.667*k < 65536-boundary slack; spot-verified
// at 40/48, 272/280/288, 432/440). Same formula used in KLOOP and msks.
// ---------------------------------------------------------------------------
#define KLOOP(GW)                                                              \
    _Pragma("unroll")                                                          \
    for (int s = 0; s < 14; ++s) {                                             \
        const char* wb = (GW) + bB + s * 3072;                                 \
        half8v bv0 = *(const half8v*)(wb);                                     \
        half8v bv1 = *(const half8v*)(wb + 256);                               \
        half8v bv2 = *(const half8v*)(wb + 512);                               \
        const int k_   = s * 32 + q * 8;                                       \
        const int tap_ = (k_ * 1366) >> 16;       /* k/48, exact for k<481 */  \
        const int kc_  = k_ - tap_ * 48;                                       \
        const int ty_  = (tap_ * 11) >> 5;        /* tap/3, exact tap<=9 */    \
        const int tx_  = tap_ - ty_ * 3;                                       \
        const int aoff_ = (kc_ >> 3) * CB_STRIDE + (ty_ * 28 + tx_) * 16;      \
        _Pragma("unroll")                                                      \
        for (int mt = 0; mt < 4; ++mt) {                                       \
            if (mt < 3 || wid == 0) {                                          \
                int ad = pixb16[mt] + aoff_;                                   \
                ad = ((msks[mt] >> s) & 1) ? ad : ZERO_OFF;                    \
                half8v a = *(const half8v*)(smem + ad);                        \
                acc[mt][0] = __builtin_amdgcn_mfma_f32_16x16x32_f16(a, bv0, acc[mt][0], 0, 0, 0); \
                acc[mt][1] = __builtin_amdgcn_mfma_f32_16x16x32_f16(a, bv1, acc[mt][1], 0, 0, 0); \
                acc[mt][2] = __builtin_amdgcn_mfma_f32_16x16x32_f16(a, bv2, acc[mt][2], 0, 0, 0); \
            }                                                                  \
        }                                                                      \
    }

__global__ __launch_bounds__(1024, 1) void fused_cnn(
    const float* __restrict__ x,              // [NFRM][784] fp32
    const float* __restrict__ w1, const float* __restrict__ b1,
    const float* __restrict__ b2, const float* __restrict__ b3,
    const unsigned short* __restrict__ wpack, // [2][21504] halfs (frag order)
    float* __restrict__ feats,                // [NFRM][48]
    const float* __restrict__ bn_g, const float* __restrict__ bn_b,
    const float* __restrict__ bn_m, const float* __restrict__ bn_v)
{
    __shared__ __align__(16) char smem[LDS_TOT];
    const int tid = threadIdx.x;
    const int n = blockIdx.x;
    const int lane = tid & 63, wid = tid >> 6;         // wid 0..15
    const int l15 = lane & 15, q = lane >> 4;

    // zero page + stage raw frame
    if (tid < 4) *(unsigned int*)(smem + ZERO_OFF + tid * 4) = 0;
    if (tid < NPIX) ((float*)(smem + X_OFF))[tid] = x[(size_t)n * NPIX + tid];
    __syncthreads();

    // ---- conv1 (1->48) on VALU, two 24-channel halves (arch-reg friendly) ----
    if (tid < NPIX) {
        const float* sx = (const float*)(smem + X_OFF);
        int y = tid / 28, xx = tid % 28;
        #pragma unroll
        for (int h = 0; h < 2; ++h) {
            float a[24];
            #pragma unroll
            for (int c = 0; c < 24; ++c) a[c] = b1[h * 24 + c];
            #pragma unroll
            for (int dy = 0; dy < 3; ++dy) {
                int yy = y + dy - 1;
                if ((unsigned)yy >= 28u) continue;
                #pragma unroll
                for (int dx = 0; dx < 3; ++dx) {
                    int xc = xx + dx - 1;
                    if ((unsigned)xc >= 28u) continue;
                    float xv = sx[yy * 28 + xc];
                    const float* wr = w1 + (dy * 3 + dx) * 48 + h * 24;
                    #pragma unroll
                    for (int c = 0; c < 24; ++c) a[c] += xv * wr[c];
                }
            }
            #pragma unroll
            for (int c2 = 0; c2 < 3; ++c2) {
                half8v hv;
                #pragma unroll
                for (int j = 0; j < 8; ++j)
                    hv[j] = (_Float16)fmaxf(a[c2 * 8 + j], 0.f);
                *(half8v*)(smem + (h * 3 + c2) * CB_STRIDE + tid * 16) = hv;
            }
        }
    }
    __syncthreads();

    // ---- per-mt constants ----
    const int bB = q * 768 + l15 * 16;     // B frag byte offset within an s-block
    const char* gw2 = (const char*)wpack;
    const char* gw3 = gw2 + WPACK;

    float4v acc[4][3];
    int pixb16[4], msks[4];
    #pragma unroll
    for (int mt = 0; mt < 4; ++mt) {
        int tt = wid + mt * 16;
        int p  = tt * 16 + l15;
        int y  = (p * 9363) >> 18;             // p/28 (pad tiles: garbage ok, masked)
        int x2 = p - y * 28;
        pixb16[mt] = (p - 29) * 16;
        unsigned my0 = ((unsigned)(y - 1) < 28u) ? 0x007u : 0u;
        unsigned my1 = ((unsigned)(y    ) < 28u) ? 0x038u : 0u;
        unsigned my2 = ((unsigned)(y + 1) < 28u) ? 0x1C0u : 0u;
        unsigned mx0 = ((unsigned)(x2 - 1) < 28u) ? 0x049u : 0u;
        unsigned mx1 = ((unsigned)(x2    ) < 28u) ? 0x092u : 0u;
        unsigned mx2 = ((unsigned)(x2 + 1) < 28u) ? 0x124u : 0u;
        unsigned m9 = (my0 | my1 | my2) & (mx0 | mx1 | mx2);
        if (tt >= 49) m9 = 0;                  // pad tiles -> zero page only
        int mm = 0;
        #pragma unroll
        for (int s = 0; s < 14; ++s) {
            int k = s * 32 + q * 8;
            int tap = (k * 1366) >> 16;        // k/48, exact for k<481
            if ((m9 >> tap) & 1) mm |= (1 << s);   // tap==9 -> bit9 of m9 == 0
        }
        msks[mt] = mm;
        #pragma unroll
        for (int nt = 0; nt < 3; ++nt) {
            float bv = b2[nt * 16 + l15];
            acc[mt][nt] = (float4v){bv, bv, bv, bv};
        }
    }

    // ---- conv2 ----
    KLOOP(gw2)

    __syncthreads();                           // conv1-act reads done

    // conv2 output (ReLU, fp16) -> act region; pair-packed b32 stores
    #pragma unroll
    for (int mt = 0; mt < 4; ++mt) {
        int tt = wid + mt * 16;
        if (tt >= 49) continue;
        #pragma unroll
        for (int nt = 0; nt < 3; ++nt) {
            int c = nt * 16 + l15;
            #pragma unroll
            for (int r = 0; r < 4; ++r) {
                int p = tt * 16 + q * 4 + r;
                unsigned int us = (unsigned int)f2h(fmaxf(acc[mt][nt][r], 0.f));
                unsigned int other = __shfl_xor(us, 1);
                if (!(l15 & 1)) {
                    unsigned int dw = us | (other << 16);
                    *(unsigned int*)(smem + (c >> 3) * CB_STRIDE + (c & 7) * 2 + p * 16) = dw;
                }
            }
        }
    }
    __syncthreads();                           // conv2 act visible

    #pragma unroll
    for (int mt = 0; mt < 4; ++mt)
        #pragma unroll
        for (int nt = 0; nt < 3; ++nt) {
            float bv = b3[nt * 16 + l15];
            acc[mt][nt] = (float4v){bv, bv, bv, bv};
        }

    // ---- conv3 ----
    KLOOP(gw3)

    // ---- fused ReLU + global-avg-pool + BN1 ----
    float ps0 = 0.f, ps1 = 0.f, ps2 = 0.f;
    #pragma unroll
    for (int mt = 0; mt < 4; ++mt) {
        int tt = wid + mt * 16;
        if (tt >= 49) continue;
        #pragma unroll
        for (int r = 0; r < 4; ++r) {
            ps0 += fmaxf(acc[mt][0][r], 0.f);
            ps1 += fmaxf(acc[mt][1][r], 0.f);
            ps2 += fmaxf(acc[mt][2][r], 0.f);
        }
    }
    ps0 += __shfl_xor(ps0, 16); ps0 += __shfl_xor(ps0, 32);
    ps1 += __shfl_xor(ps1, 16); ps1 += __shfl_xor(ps1, 32);
    ps2 += __shfl_xor(ps2, 16); ps2 += __shfl_xor(ps2, 32);
    __syncthreads();                           // act region dead; alias as reduce buf
    float* sRed = (float*)smem;
    if (lane < 16) {
        sRed[wid * 48 + l15]      = ps0;
        sRed[wid * 48 + 16 + l15] = ps1;
        sRed[wid * 48 + 32 + l15] = ps2;
    }
    __syncthreads();
    if (tid < 48) {
        float s = 0.f;
        #pragma unroll
        for (int wv = 0; wv < 16; ++wv) s += sRed[wv * 48 + tid];
        float r  = rsqrtf(bn_v[tid] + EPSV);
        float sc = r * bn_g[tid] * (1.0f / 784.0f);
        float sh = bn_b[tid] - bn_m[tid] * r * bn_g[tid];
        feats[(size_t)n * 48 + tid] = s * sc + sh;
    }
}

// ---------------------------------------------------------------------------
// Kernel 2: LSTM + BN2 + dense head. One wave per batch element.
// ---------------------------------------------------------------------------
__global__ __launch_bounds__(64) void lstm_kernel(
    const float* __restrict__ feats,
    const float* __restrict__ wf, const float* __restrict__ bfv,
    const float* __restrict__ wi1, const float* __restrict__ bi1,
    const float* __restrict__ wi2, const float* __restrict__ bi2,
    const float* __restrict__ wo, const float* __restrict__ bov,
    const float* __restrict__ g2, const float* __restrict__ b2v,
    const float* __restrict__ m2, const float* __restrict__ v2,
    const float* __restrict__ w_out, const float* __restrict__ b_out,
    float* __restrict__ out)
{
    __shared__ float sZ[56];     // [0,48) = x_t, [48,56) = h
    __shared__ float sG[32];     // gates f,i,g,o
    __shared__ float sS[8];
    __shared__ float sKs;

    int tid = threadIdx.x;
    int b = blockIdx.x;
    int gu = tid & 31, g = gu >> 3, u = gu & 7, half = tid >> 5;

    const float* wsrc = (g == 0) ? wf : (g == 1) ? wi1 : (g == 2) ? wi2 : wo;
    float wreg[28];
    #pragma unroll
    for (int j = 0; j < 28; ++j) wreg[j] = wsrc[(half * 28 + j) * 8 + u];
    float bias = ((g == 0) ? bfv : (g == 1) ? bi1 : (g == 2) ? bi2 : bov)[u];

    if (tid < 8) {
        float r = rsqrtf(v2[tid] + EPSV);
        sS[tid] = r * g2[tid] * w_out[tid];
        sZ[48 + tid] = 0.f;
    }
    if (tid == 0) {
        float k = b_out[0];
        for (int uu = 0; uu < 8; ++uu) {
            float r = rsqrtf(v2[uu] + EPSV);
            k += (b2v[uu] - m2[uu] * r * g2[uu]) * w_out[uu];
        }
        sKs = k;
    }

    float c = 0.f;
    const float* fb = feats + (size_t)b * T_ * 48;

    for (int t = 0; t < T_; ++t) {
        if (tid < 48) sZ[tid] = fb[t * 48 + tid];
        __syncthreads();

        float a = 0.f;
        #pragma unroll
        for (int j = 0; j < 28; ++j) a += sZ[half * 28 + j] * wreg[j];
        a += __shfl_xor(a, 32);
        a += bias;
        float v;
        if (g == 2) { float e = __expf(2.f * a); v = 1.f - 2.f / (e + 1.f); }
        else        { v = 1.f / (1.f + __expf(-a)); }
        if (tid < 32) sG[gu] = v;
        __syncthreads();

        if (tid < 8) {
            c = sG[tid] * c + sG[8 + tid] * sG[16 + tid];
            float e = __expf(2.f * c);
            float h = sG[24 + tid] * (1.f - 2.f / (e + 1.f));
            sZ[48 + tid] = h;
            float contrib = h * sS[tid];
            contrib += __shfl_xor(contrib, 1);
            contrib += __shfl_xor(contrib, 2);
            contrib += __shfl_xor(contrib, 4);
            if (tid == 0) out[b * T_ + t] = contrib + sKs;
        }
        __syncthreads();
    }
}

// ---------------------------------------------------------------------------
extern "C" void kernel_launch(void* const* d_in, const int* in_sizes, int n_in,
                              void* d_out, int out_size, void* d_ws, size_t ws_size,
                              hipStream_t stream)
{
    const float* x    = (const float*)d_in[0];
    const float* w1   = (const float*)d_in[1];
    const float* b1   = (const float*)d_in[2];
    const float* w2   = (const float*)d_in[3];
    const float* b2   = (const float*)d_in[4];
    const float* w3   = (const float*)d_in[5];
    const float* b3   = (const float*)d_in[6];
    const float* bn1g = (const float*)d_in[7];
    const float* bn1b = (const float*)d_in[8];
    const float* bn1m = (const float*)d_in[9];
    const float* bn1v = (const float*)d_in[10];
    const float* wf   = (const float*)d_in[11];
    const float* bf   = (const float*)d_in[12];
    const float* wi1  = (const float*)d_in[13];
    const float* bi1  = (const float*)d_in[14];
    const float* wi2  = (const float*)d_in[15];
    const float* bi2  = (const float*)d_in[16];
    const float* wo   = (const float*)d_in[17];
    const float* bo   = (const float*)d_in[18];
    const float* bn2g = (const float*)d_in[19];
    const float* bn2b = (const float*)d_in[20];
    const float* bn2m = (const float*)d_in[21];
    const float* bn2v = (const float*)d_in[22];
    const float* wout = (const float*)d_in[23];
    const float* bout = (const float*)d_in[24];

    unsigned short* wpack = (unsigned short*)d_ws;            // 2*43008 B
    float* feats = (float*)((char*)d_ws + 2 * WPACK);         // 1024*48 fp32
    const size_t need = 2 * WPACK + (size_t)NFRM * 48 * 4;
    if (ws_size < need) return;

    pack_weights<<<168, 256, 0, stream>>>(w2, w3, wpack);
    fused_cnn<<<NFRM, 1024, 0, stream>>>(x, w1, b1, b2, b3, wpack, feats,
                                         bn1g, bn1b, bn1m, bn1v);
    lstm_kernel<<<B_, 64, 0, stream>>>(feats, wf, bf, wi1, bi1, wi2, bi2, wo, bo,
                                       bn2g, bn2b, bn2m, bn2v, wout, bout,
                                       (float*)d_out);
}

// Round 10
// 129.459 us; speedup vs baseline: 1.0866x; 1.0866x over previous
//
#include <hip/hip_runtime.h>
#include <stdint.h>

#define B_ 32
#define T_ 32
#define NPIX 784
#define NFRM 1024
#define EPSV 1e-3f

typedef __attribute__((ext_vector_type(8))) _Float16 half8v;
typedef __attribute__((ext_vector_type(4))) float float4v;

// ---- LDS map (bytes) ----
// act region [0, 75456)       : fp16 acts, 6 cb * 12576 B; chunk = (cb, pixel) 16B
// zero page  [75456, 75472)
// x region   [75472, 78608)   : raw frame fp32 (784*4)
#define CB_STRIDE 12576
#define ZERO_OFF  75456
#define X_OFF     75472
#define LDS_TOT   78608
#define WPACK     43008              // bytes per conv weight pack

__device__ __forceinline__ unsigned short f2h(float f) {
    union { _Float16 h; unsigned short u; } cv; cv.h = (_Float16)f; return cv.u;
}

// ---------------------------------------------------------------------------
// Kernel 0: pack w2/w3 as fp16 in MFMA-B fragment order [s][q][co][j].
// k = s*32 + q*8 + j = tap*48 + cin ; k >= 432 zero-padded.
// ---------------------------------------------------------------------------
__global__ __launch_bounds__(256) void pack_weights(
    const float* __restrict__ w2, const float* __restrict__ w3,
    unsigned short* __restrict__ out)
{
    int idx = blockIdx.x * 256 + threadIdx.x;     // 0 .. 43007
    int conv = idx / 21504;
    int r = idx - conv * 21504;
    const float* w = conv ? w3 : w2;
    int s  = r / 1536;
    int r2 = r - s * 1536;
    int q  = r2 / 384;
    int r3 = r2 - q * 384;
    int co = r3 >> 3, j = r3 & 7;
    int k  = s * 32 + q * 8 + j;
    unsigned short v = 0;
    if (k < 432) v = f2h(w[k * 48 + co]);
    out[idx] = v;
}

// ---------------------------------------------------------------------------
// Fused conv1 + conv2 + conv3 (fp16 MFMA) + ReLU + avgpool + BN1.
// One block = one frame; 1024 threads = 16 waves; wave w owns tiles tt=w+16*mt.
// Register model (R5-R9): per-SIMD pool = 512 regs/wave-slot; 1024-thr block
// -> 4 waves/SIMD -> <=128 total/wave; gfx950 compiler splits 64 arch + 64
// AGPR when MFMA present (R9: VGPR_Count=64, occupancy 41%). acc=48 AGPR fits;
// arch must stay <=64 -> K-loop at #pragma unroll 2 (full unroll let the
// scheduler hoist B-loads -> 118 MB spill in R9). tap=k/48 via (k*1366)>>16,
// exact for k<481 (R8 fix, verified at all q*8+s*32 points).
// ---------------------------------------------------------------------------
#define KLOOP(GW)                                                              \
    _Pragma("unroll 2")                                                        \
    for (int s = 0; s < 14; ++s) {                                             \
        const char* wb = (GW) + bB + s * 3072;                                 \
        half8v bv0 = *(const half8v*)(wb);                                     \
        half8v bv1 = *(const half8v*)(wb + 256);                               \
        half8v bv2 = *(const half8v*)(wb + 512);                               \
        const int k_   = s * 32 + q * 8;                                       \
        const int tap_ = (k_ * 1366) >> 16;       /* k/48, exact for k<481 */  \
        const int kc_  = k_ - tap_ * 48;                                       \
        const int ty_  = (tap_ * 11) >> 5;        /* tap/3, exact tap<=9 */    \
        const int tx_  = tap_ - ty_ * 3;                                       \
        const int aoff_ = (kc_ >> 3) * CB_STRIDE + (ty_ * 28 + tx_) * 16;      \
        _Pragma("unroll")                                                      \
        for (int mt = 0; mt < 4; ++mt) {                                       \
            if (mt < 3 || wid == 0) {                                          \
                int ad = pixb16[mt] + aoff_;                                   \
                ad = ((msks[mt] >> s) & 1) ? ad : ZERO_OFF;                    \
                half8v a = *(const half8v*)(smem + ad);                        \
                acc[mt][0] = __builtin_amdgcn_mfma_f32_16x16x32_f16(a, bv0, acc[mt][0], 0, 0, 0); \
                acc[mt][1] = __builtin_amdgcn_mfma_f32_16x16x32_f16(a, bv1, acc[mt][1], 0, 0, 0); \
                acc[mt][2] = __builtin_amdgcn_mfma_f32_16x16x32_f16(a, bv2, acc[mt][2], 0, 0, 0); \
            }                                                                  \
        }                                                                      \
    }

__global__ __launch_bounds__(1024, 1) void fused_cnn(
    const float* __restrict__ x,              // [NFRM][784] fp32
    const float* __restrict__ w1, const float* __restrict__ b1,
    const float* __restrict__ b2, const float* __restrict__ b3,
    const unsigned short* __restrict__ wpack, // [2][21504] halfs (frag order)
    float* __restrict__ feats,                // [NFRM][48]
    const float* __restrict__ bn_g, const float* __restrict__ bn_b,
    const float* __restrict__ bn_m, const float* __restrict__ bn_v)
{
    __shared__ __align__(16) char smem[LDS_TOT];
    const int tid = threadIdx.x;
    const int n = blockIdx.x;
    const int lane = tid & 63, wid = tid >> 6;         // wid 0..15
    const int l15 = lane & 15, q = lane >> 4;

    // zero page + stage raw frame
    if (tid < 4) *(unsigned int*)(smem + ZERO_OFF + tid * 4) = 0;
    if (tid < NPIX) ((float*)(smem + X_OFF))[tid] = x[(size_t)n * NPIX + tid];
    __syncthreads();

    // ---- conv1 (1->48) on VALU, two 24-channel halves (arch-reg friendly) ----
    if (tid < NPIX) {
        const float* sx = (const float*)(smem + X_OFF);
        int y = tid / 28, xx = tid % 28;
        #pragma unroll
        for (int h = 0; h < 2; ++h) {
            float a[24];
            #pragma unroll
            for (int c = 0; c < 24; ++c) a[c] = b1[h * 24 + c];
            #pragma unroll
            for (int dy = 0; dy < 3; ++dy) {
                int yy = y + dy - 1;
                if ((unsigned)yy >= 28u) continue;
                #pragma unroll
                for (int dx = 0; dx < 3; ++dx) {
                    int xc = xx + dx - 1;
                    if ((unsigned)xc >= 28u) continue;
                    float xv = sx[yy * 28 + xc];
                    const float* wr = w1 + (dy * 3 + dx) * 48 + h * 24;
                    #pragma unroll
                    for (int c = 0; c < 24; ++c) a[c] += xv * wr[c];
                }
            }
            #pragma unroll
            for (int c2 = 0; c2 < 3; ++c2) {
                half8v hv;
                #pragma unroll
                for (int j = 0; j < 8; ++j)
                    hv[j] = (_Float16)fmaxf(a[c2 * 8 + j], 0.f);
                *(half8v*)(smem + (h * 3 + c2) * CB_STRIDE + tid * 16) = hv;
            }
        }
    }
    __syncthreads();

    // ---- per-mt constants ----
    const int bB = q * 768 + l15 * 16;     // B frag byte offset within an s-block
    const char* gw2 = (const char*)wpack;
    const char* gw3 = gw2 + WPACK;

    float4v acc[4][3];
    int pixb16[4], msks[4];
    #pragma unroll
    for (int mt = 0; mt < 4; ++mt) {
        int tt = wid + mt * 16;
        int p  = tt * 16 + l15;
        int y  = (p * 9363) >> 18;             // p/28 (pad tiles: garbage ok, masked)
        int x2 = p - y * 28;
        pixb16[mt] = (p - 29) * 16;
        unsigned my0 = ((unsigned)(y - 1) < 28u) ? 0x007u : 0u;
        unsigned my1 = ((unsigned)(y    ) < 28u) ? 0x038u : 0u;
        unsigned my2 = ((unsigned)(y + 1) < 28u) ? 0x1C0u : 0u;
        unsigned mx0 = ((unsigned)(x2 - 1) < 28u) ? 0x049u : 0u;
        unsigned mx1 = ((unsigned)(x2    ) < 28u) ? 0x092u : 0u;
        unsigned mx2 = ((unsigned)(x2 + 1) < 28u) ? 0x124u : 0u;
        unsigned m9 = (my0 | my1 | my2) & (mx0 | mx1 | mx2);
        if (tt >= 49) m9 = 0;                  // pad tiles -> zero page only
        int mm = 0;
        #pragma unroll
        for (int s = 0; s < 14; ++s) {
            int k = s * 32 + q * 8;
            int tap = (k * 1366) >> 16;        // k/48, exact for k<481
            if ((m9 >> tap) & 1) mm |= (1 << s);   // tap==9 -> bit9 of m9 == 0
        }
        msks[mt] = mm;
        #pragma unroll
        for (int nt = 0; nt < 3; ++nt) {
            float bv = b2[nt * 16 + l15];
            acc[mt][nt] = (float4v){bv, bv, bv, bv};
        }
    }

    // ---- conv2 ----
    KLOOP(gw2)

    __syncthreads();                           // conv1-act reads done

    // conv2 output (ReLU, fp16) -> act region; pair-packed b32 stores
    #pragma unroll
    for (int mt = 0; mt < 4; ++mt) {
        int tt = wid + mt * 16;
        if (tt >= 49) continue;
        #pragma unroll
        for (int nt = 0; nt < 3; ++nt) {
            int c = nt * 16 + l15;
            #pragma unroll
            for (int r = 0; r < 4; ++r) {
                int p = tt * 16 + q * 4 + r;
                unsigned int us = (unsigned int)f2h(fmaxf(acc[mt][nt][r], 0.f));
                unsigned int other = __shfl_xor(us, 1);
                if (!(l15 & 1)) {
                    unsigned int dw = us | (other << 16);
                    *(unsigned int*)(smem + (c >> 3) * CB_STRIDE + (c & 7) * 2 + p * 16) = dw;
                }
            }
        }
    }
    __syncthreads();                           // conv2 act visible

    #pragma unroll
    for (int mt = 0; mt < 4; ++mt)
        #pragma unroll
        for (int nt = 0; nt < 3; ++nt) {
            float bv = b3[nt * 16 + l15];
            acc[mt][nt] = (float4v){bv, bv, bv, bv};
        }

    // ---- conv3 ----
    KLOOP(gw3)

    // ---- fused ReLU + global-avg-pool + BN1 ----
    float ps0 = 0.f, ps1 = 0.f, ps2 = 0.f;
    #pragma unroll
    for (int mt = 0; mt < 4; ++mt) {
        int tt = wid + mt * 16;
        if (tt >= 49) continue;
        #pragma unroll
        for (int r = 0; r < 4; ++r) {
            ps0 += fmaxf(acc[mt][0][r], 0.f);
            ps1 += fmaxf(acc[mt][1][r], 0.f);
            ps2 += fmaxf(acc[mt][2][r], 0.f);
        }
    }
    ps0 += __shfl_xor(ps0, 16); ps0 += __shfl_xor(ps0, 32);
    ps1 += __shfl_xor(ps1, 16); ps1 += __shfl_xor(ps1, 32);
    ps2 += __shfl_xor(ps2, 16); ps2 += __shfl_xor(ps2, 32);
    __syncthreads();                           // act region dead; alias as reduce buf
    float* sRed = (float*)smem;
    if (lane < 16) {
        sRed[wid * 48 + l15]      = ps0;
        sRed[wid * 48 + 16 + l15] = ps1;
        sRed[wid * 48 + 32 + l15] = ps2;
    }
    __syncthreads();
    if (tid < 48) {
        float s = 0.f;
        #pragma unroll
        for (int wv = 0; wv < 16; ++wv) s += sRed[wv * 48 + tid];
        float r  = rsqrtf(bn_v[tid] + EPSV);
        float sc = r * bn_g[tid] * (1.0f / 784.0f);
        float sh = bn_b[tid] - bn_m[tid] * r * bn_g[tid];
        feats[(size_t)n * 48 + tid] = s * sc + sh;
    }
}

// ---------------------------------------------------------------------------
// Kernel 2: LSTM + BN2 + dense head. One wave per batch element.
// ---------------------------------------------------------------------------
__global__ __launch_bounds__(64) void lstm_kernel(
    const float* __restrict__ feats,
    const float* __restrict__ wf, const float* __restrict__ bfv,
    const float* __restrict__ wi1, const float* __restrict__ bi1,
    const float* __restrict__ wi2, const float* __restrict__ bi2,
    const float* __restrict__ wo, const float* __restrict__ bov,
    const float* __restrict__ g2, const float* __restrict__ b2v,
    const float* __restrict__ m2, const float* __restrict__ v2,
    const float* __restrict__ w_out, const float* __restrict__ b_out,
    float* __restrict__ out)
{
    __shared__ float sZ[56];     // [0,48) = x_t, [48,56) = h
    __shared__ float sG[32];     // gates f,i,g,o
    __shared__ float sS[8];
    __shared__ float sKs;

    int tid = threadIdx.x;
    int b = blockIdx.x;
    int gu = tid & 31, g = gu >> 3, u = gu & 7, half = tid >> 5;

    const float* wsrc = (g == 0) ? wf : (g == 1) ? wi1 : (g == 2) ? wi2 : wo;
    float wreg[28];
    #pragma unroll
    for (int j = 0; j < 28; ++j) wreg[j] = wsrc[(half * 28 + j) * 8 + u];
    float bias = ((g == 0) ? bfv : (g == 1) ? bi1 : (g == 2) ? bi2 : bov)[u];

    if (tid < 8) {
        float r = rsqrtf(v2[tid] + EPSV);
        sS[tid] = r * g2[tid] * w_out[tid];
        sZ[48 + tid] = 0.f;
    }
    if (tid == 0) {
        float k = b_out[0];
        for (int uu = 0; uu < 8; ++uu) {
            float r = rsqrtf(v2[uu] + EPSV);
            k += (b2v[uu] - m2[uu] * r * g2[uu]) * w_out[uu];
        }
        sKs = k;
    }

    float c = 0.f;
    const float* fb = feats + (size_t)b * T_ * 48;

    for (int t = 0; t < T_; ++t) {
        if (tid < 48) sZ[tid] = fb[t * 48 + tid];
        __syncthreads();

        float a = 0.f;
        #pragma unroll
        for (int j = 0; j < 28; ++j) a += sZ[half * 28 + j] * wreg[j];
        a += __shfl_xor(a, 32);
        a += bias;
        float v;
        if (g == 2) { float e = __expf(2.f * a); v = 1.f - 2.f / (e + 1.f); }
        else        { v = 1.f / (1.f + __expf(-a)); }
        if (tid < 32) sG[gu] = v;
        __syncthreads();

        if (tid < 8) {
            c = sG[tid] * c + sG[8 + tid] * sG[16 + tid];
            float e = __expf(2.f * c);
            float h = sG[24 + tid] * (1.f - 2.f / (e + 1.f));
            sZ[48 + tid] = h;
            float contrib = h * sS[tid];
            contrib += __shfl_xor(contrib, 1);
            contrib += __shfl_xor(contrib, 2);
            contrib += __shfl_xor(contrib, 4);
            if (tid == 0) out[b * T_ + t] = contrib + sKs;
        }
        __syncthreads();
    }
}

// ---------------------------------------------------------------------------
extern "C" void kernel_launch(void* const* d_in, const int* in_sizes, int n_in,
                              void* d_out, int out_size, void* d_ws, size_t ws_size,
                              hipStream_t stream)
{
    const float* x    = (const float*)d_in[0];
    const float* w1   = (const float*)d_in[1];
    const float* b1   = (const float*)d_in[2];
    const float* w2   = (const float*)d_in[3];
    const float* b2   = (const float*)d_in[4];
    const float* w3   = (const float*)d_in[5];
    const float* b3   = (const float*)d_in[6];
    const float* bn1g = (const float*)d_in[7];
    const float* bn1b = (const float*)d_in[8];
    const float* bn1m = (const float*)d_in[9];
    const float* bn1v = (const float*)d_in[10];
    const float* wf   = (const float*)d_in[11];
    const float* bf   = (const float*)d_in[12];
    const float* wi1  = (const float*)d_in[13];
    const float* bi1  = (const float*)d_in[14];
    const float* wi2  = (const float*)d_in[15];
    const float* bi2  = (const float*)d_in[16];
    const float* wo   = (const float*)d_in[17];
    const float* bo   = (const float*)d_in[18];
    const float* bn2g = (const float*)d_in[19];
    const float* bn2b = (const float*)d_in[20];
    const float* bn2m = (const float*)d_in[21];
    const float* bn2v = (const float*)d_in[22];
    const float* wout = (const float*)d_in[23];
    const float* bout = (const float*)d_in[24];

    unsigned short* wpack = (unsigned short*)d_ws;            // 2*43008 B
    float* feats = (float*)((char*)d_ws + 2 * WPACK);         // 1024*48 fp32
    const size_t need = 2 * WPACK + (size_t)NFRM * 48 * 4;
    if (ws_size < need) return;

    pack_weights<<<168, 256, 0, stream>>>(w2, w3, wpack);
    fused_cnn<<<NFRM, 1024, 0, stream>>>(x, w1, b1, b2, b3, wpack, feats,
                                         bn1g, bn1b, bn1m, bn1v);
    lstm_kernel<<<B_, 64, 0, stream>>>(feats, wf, bf, wi1, bi1, wi2, bi2, wo, bo,
                                       bn2g, bn2b, bn2m, bn2v, wout, bout,
                                       (float*)d_out);
}

// Round 11
// 123.651 us; speedup vs baseline: 1.1376x; 1.0470x over previous
//
#include <hip/hip_runtime.h>
#include <stdint.h>

#define B_ 32
#define T_ 32
#define NPIX 784
#define NFRM 1024
#define EPSV 1e-3f

typedef __attribute__((ext_vector_type(8))) _Float16 half8v;
typedef __attribute__((ext_vector_type(4))) float float4v;

// ---- LDS map (bytes) ----
// act region [0, 75456)       : fp16 acts, 6 cb * 12576 B; chunk = (cb, pixel) 16B
// zero page  [75456, 75472)
// x region   [75472, 78608)   : raw frame fp32 (784*4)
// W region   [78608, 121616)  : one conv's fp16 weight pack (staged per conv)
#define CB_STRIDE 12576
#define ZERO_OFF  75456
#define X_OFF     75472
#define W_OFF     78608
#define LDS_TOT   121616             // <= 163840 -> 1 block x 16 waves/CU
#define WPACK     43008              // bytes per conv weight pack

__device__ __forceinline__ unsigned short f2h(float f) {
    union { _Float16 h; unsigned short u; } cv; cv.h = (_Float16)f; return cv.u;
}

// ---------------------------------------------------------------------------
// Kernel 0: pack w2/w3 as fp16 in MFMA-B fragment order [s][q][co][j].
// k = s*32 + q*8 + j = tap*48 + cin ; k >= 432 zero-padded.
// ---------------------------------------------------------------------------
__global__ __launch_bounds__(256) void pack_weights(
    const float* __restrict__ w2, const float* __restrict__ w3,
    unsigned short* __restrict__ out)
{
    int idx = blockIdx.x * 256 + threadIdx.x;     // 0 .. 43007
    int conv = idx / 21504;
    int r = idx - conv * 21504;
    const float* w = conv ? w3 : w2;
    int s  = r / 1536;
    int r2 = r - s * 1536;
    int q  = r2 / 384;
    int r3 = r2 - q * 384;
    int co = r3 >> 3, j = r3 & 7;
    int k  = s * 32 + q * 8 + j;
    unsigned short v = 0;
    if (k < 432) v = f2h(w[k * 48 + co]);
    out[idx] = v;
}

// ---------------------------------------------------------------------------
// async stage of one 43008-B weight pack, global -> LDS W region (linear).
// 2688 16B chunks over 1024 threads: 2 full sweeps + 640-thread tail.
// LDS dest = wave-uniform base (W_OFF + wid*1024 [+16384k]) + lane*16  -> legal.
// ---------------------------------------------------------------------------
__device__ __forceinline__ void stage_w(char* smem, const char* g, int tid) {
    const char* gl = g + tid * 16;
    __builtin_amdgcn_global_load_lds(
        (const __attribute__((address_space(1))) unsigned int*)(gl),
        (__attribute__((address_space(3))) unsigned int*)(smem + W_OFF + tid * 16),
        16, 0, 0);
    __builtin_amdgcn_global_load_lds(
        (const __attribute__((address_space(1))) unsigned int*)(gl + 16384),
        (__attribute__((address_space(3))) unsigned int*)(smem + W_OFF + tid * 16 + 16384),
        16, 0, 0);
    if (tid < 640)
        __builtin_amdgcn_global_load_lds(
            (const __attribute__((address_space(1))) unsigned int*)(gl + 32768),
            (__attribute__((address_space(3))) unsigned int*)(smem + W_OFF + tid * 16 + 32768),
            16, 0, 0);
}

// ---------------------------------------------------------------------------
// Fused conv1 + conv2 + conv3 (fp16 MFMA) + ReLU + avgpool + BN1.
// One block = one frame; 1024 threads = 16 waves; wave w owns tiles tt=w+16*mt.
// Register model (R5-R10): per-SIMD pool 512 regs/wave-slot; 16-wave block ->
// <=128 total/wave; K-loop at unroll 2 keeps arch ~52 (R10: no spill).
// R10->R11: B operand moved global->LDS (43KB pack > 32KB L1 thrashed to L2,
// ~250cy exposed per s-step; ds_read ~60cy hides under 4 waves/SIMD).
// tap=k/48 via (k*1366)>>16, exact for k<481 (R8 fix).
// ---------------------------------------------------------------------------
#define KLOOP                                                                  \
    _Pragma("unroll 2")                                                        \
    for (int s = 0; s < 14; ++s) {                                             \
        const char* wb = smem + W_OFF + bB + s * 3072;                         \
        half8v bv0 = *(const half8v*)(wb);                                     \
        half8v bv1 = *(const half8v*)(wb + 256);                               \
        half8v bv2 = *(const half8v*)(wb + 512);                               \
        const int k_   = s * 32 + q * 8;                                       \
        const int tap_ = (k_ * 1366) >> 16;       /* k/48, exact for k<481 */  \
        const int kc_  = k_ - tap_ * 48;                                       \
        const int ty_  = (tap_ * 11) >> 5;        /* tap/3, exact tap<=9 */    \
        const int tx_  = tap_ - ty_ * 3;                                       \
        const int aoff_ = (kc_ >> 3) * CB_STRIDE + (ty_ * 28 + tx_) * 16;      \
        _Pragma("unroll")                                                      \
        for (int mt = 0; mt < 4; ++mt) {                                       \
            if (mt < 3 || wid == 0) {                                          \
                int ad = pixb16[mt] + aoff_;                                   \
                ad = ((msks[mt] >> s) & 1) ? ad : ZERO_OFF;                    \
                half8v a = *(const half8v*)(smem + ad);                        \
                acc[mt][0] = __builtin_amdgcn_mfma_f32_16x16x32_f16(a, bv0, acc[mt][0], 0, 0, 0); \
                acc[mt][1] = __builtin_amdgcn_mfma_f32_16x16x32_f16(a, bv1, acc[mt][1], 0, 0, 0); \
                acc[mt][2] = __builtin_amdgcn_mfma_f32_16x16x32_f16(a, bv2, acc[mt][2], 0, 0, 0); \
            }                                                                  \
        }                                                                      \
    }

__global__ __launch_bounds__(1024, 1) void fused_cnn(
    const float* __restrict__ x,              // [NFRM][784] fp32
    const float* __restrict__ w1, const float* __restrict__ b1,
    const float* __restrict__ b2, const float* __restrict__ b3,
    const unsigned short* __restrict__ wpack, // [2][21504] halfs (frag order)
    float* __restrict__ feats,                // [NFRM][48]
    const float* __restrict__ bn_g, const float* __restrict__ bn_b,
    const float* __restrict__ bn_m, const float* __restrict__ bn_v)
{
    __shared__ __align__(16) char smem[LDS_TOT];
    const int tid = threadIdx.x;
    const int n = blockIdx.x;
    const int lane = tid & 63, wid = tid >> 6;         // wid 0..15
    const int l15 = lane & 15, q = lane >> 4;

    // zero page + stage raw frame + async w2 stage (drains at next barrier)
    if (tid < 4) *(unsigned int*)(smem + ZERO_OFF + tid * 4) = 0;
    if (tid < NPIX) ((float*)(smem + X_OFF))[tid] = x[(size_t)n * NPIX + tid];
    stage_w(smem, (const char*)wpack, tid);
    __syncthreads();

    // ---- conv1 (1->48) on VALU, two 24-channel halves (w2 latency hides here) ----
    if (tid < NPIX) {
        const float* sx = (const float*)(smem + X_OFF);
        int y = tid / 28, xx = tid % 28;
        #pragma unroll
        for (int h = 0; h < 2; ++h) {
            float a[24];
            #pragma unroll
            for (int c = 0; c < 24; ++c) a[c] = b1[h * 24 + c];
            #pragma unroll
            for (int dy = 0; dy < 3; ++dy) {
                int yy = y + dy - 1;
                if ((unsigned)yy >= 28u) continue;
                #pragma unroll
                for (int dx = 0; dx < 3; ++dx) {
                    int xc = xx + dx - 1;
                    if ((unsigned)xc >= 28u) continue;
                    float xv = sx[yy * 28 + xc];
                    const float* wr = w1 + (dy * 3 + dx) * 48 + h * 24;
                    #pragma unroll
                    for (int c = 0; c < 24; ++c) a[c] += xv * wr[c];
                }
            }
            #pragma unroll
            for (int c2 = 0; c2 < 3; ++c2) {
                half8v hv;
                #pragma unroll
                for (int j = 0; j < 8; ++j)
                    hv[j] = (_Float16)fmaxf(a[c2 * 8 + j], 0.f);
                *(half8v*)(smem + (h * 3 + c2) * CB_STRIDE + tid * 16) = hv;
            }
        }
    }
    __syncthreads();                           // conv1 act + w2 both visible

    // ---- per-mt constants ----
    const int bB = q * 768 + l15 * 16;     // B frag byte offset within an s-block

    float4v acc[4][3];
    int pixb16[4], msks[4];
    #pragma unroll
    for (int mt = 0; mt < 4; ++mt) {
        int tt = wid + mt * 16;
        int p  = tt * 16 + l15;
        int y  = (p * 9363) >> 18;             // p/28 (pad tiles: garbage ok, masked)
        int x2 = p - y * 28;
        pixb16[mt] = (p - 29) * 16;
        unsigned my0 = ((unsigned)(y - 1) < 28u) ? 0x007u : 0u;
        unsigned my1 = ((unsigned)(y    ) < 28u) ? 0x038u : 0u;
        unsigned my2 = ((unsigned)(y + 1) < 28u) ? 0x1C0u : 0u;
        unsigned mx0 = ((unsigned)(x2 - 1) < 28u) ? 0x049u : 0u;
        unsigned mx1 = ((unsigned)(x2    ) < 28u) ? 0x092u : 0u;
        unsigned mx2 = ((unsigned)(x2 + 1) < 28u) ? 0x124u : 0u;
        unsigned m9 = (my0 | my1 | my2) & (mx0 | mx1 | mx2);
        if (tt >= 49) m9 = 0;                  // pad tiles -> zero page only
        int mm = 0;
        #pragma unroll
        for (int s = 0; s < 14; ++s) {
            int k = s * 32 + q * 8;
            int tap = (k * 1366) >> 16;        // k/48, exact for k<481
            if ((m9 >> tap) & 1) mm |= (1 << s);   // tap==9 -> bit9 of m9 == 0
        }
        msks[mt] = mm;
        #pragma unroll
        for (int nt = 0; nt < 3; ++nt) {
            float bv = b2[nt * 16 + l15];
            acc[mt][nt] = (float4v){bv, bv, bv, bv};
        }
    }

    // ---- conv2 (B from LDS) ----
    KLOOP

    __syncthreads();                           // conv1-act + w2 reads done

    // conv2 output (ReLU, fp16) -> act region; pair-packed b32 stores
    #pragma unroll
    for (int mt = 0; mt < 4; ++mt) {
        int tt = wid + mt * 16;
        if (tt >= 49) continue;
        #pragma unroll
        for (int nt = 0; nt < 3; ++nt) {
            int c = nt * 16 + l15;
            #pragma unroll
            for (int r = 0; r < 4; ++r) {
                int p = tt * 16 + q * 4 + r;
                unsigned int us = (unsigned int)f2h(fmaxf(acc[mt][nt][r], 0.f));
                unsigned int other = __shfl_xor(us, 1);
                if (!(l15 & 1)) {
                    unsigned int dw = us | (other << 16);
                    *(unsigned int*)(smem + (c >> 3) * CB_STRIDE + (c & 7) * 2 + p * 16) = dw;
                }
            }
        }
    }
    stage_w(smem, (const char*)wpack + WPACK, tid);   // w3 (async; W reads done)
    __syncthreads();                           // conv2 act + w3 visible

    #pragma unroll
    for (int mt = 0; mt < 4; ++mt)
        #pragma unroll
        for (int nt = 0; nt < 3; ++nt) {
            float bv = b3[nt * 16 + l15];
            acc[mt][nt] = (float4v){bv, bv, bv, bv};
        }

    // ---- conv3 (B from LDS) ----
    KLOOP

    // ---- fused ReLU + global-avg-pool + BN1 ----
    float ps0 = 0.f, ps1 = 0.f, ps2 = 0.f;
    #pragma unroll
    for (int mt = 0; mt < 4; ++mt) {
        int tt = wid + mt * 16;
        if (tt >= 49) continue;
        #pragma unroll
        for (int r = 0; r < 4; ++r) {
            ps0 += fmaxf(acc[mt][0][r], 0.f);
            ps1 += fmaxf(acc[mt][1][r], 0.f);
            ps2 += fmaxf(acc[mt][2][r], 0.f);
        }
    }
    ps0 += __shfl_xor(ps0, 16); ps0 += __shfl_xor(ps0, 32);
    ps1 += __shfl_xor(ps1, 16); ps1 += __shfl_xor(ps1, 32);
    ps2 += __shfl_xor(ps2, 16); ps2 += __shfl_xor(ps2, 32);
    __syncthreads();                           // act region dead; alias as reduce buf
    float* sRed = (float*)smem;
    if (lane < 16) {
        sRed[wid * 48 + l15]      = ps0;
        sRed[wid * 48 + 16 + l15] = ps1;
        sRed[wid * 48 + 32 + l15] = ps2;
    }
    __syncthreads();
    if (tid < 48) {
        float s = 0.f;
        #pragma unroll
        for (int wv = 0; wv < 16; ++wv) s += sRed[wv * 48 + tid];
        float r  = rsqrtf(bn_v[tid] + EPSV);
        float sc = r * bn_g[tid] * (1.0f / 784.0f);
        float sh = bn_b[tid] - bn_m[tid] * r * bn_g[tid];
        feats[(size_t)n * 48 + tid] = s * sc + sh;
    }
}

// ---------------------------------------------------------------------------
// Kernel 2: LSTM + BN2 + dense head. One wave per batch element.
// ---------------------------------------------------------------------------
__global__ __launch_bounds__(64) void lstm_kernel(
    const float* __restrict__ feats,
    const float* __restrict__ wf, const float* __restrict__ bfv,
    const float* __restrict__ wi1, const float* __restrict__ bi1,
    const float* __restrict__ wi2, const float* __restrict__ bi2,
    const float* __restrict__ wo, const float* __restrict__ bov,
    const float* __restrict__ g2, const float* __restrict__ b2v,
    const float* __restrict__ m2, const float* __restrict__ v2,
    const float* __restrict__ w_out, const float* __restrict__ b_out,
    float* __restrict__ out)
{
    __shared__ float sZ[56];     // [0,48) = x_t, [48,56) = h
    __shared__ float sG[32];     // gates f,i,g,o
    __shared__ float sS[8];
    __shared__ float sKs;

    int tid = threadIdx.x;
    int b = blockIdx.x;
    int gu = tid & 31, g = gu >> 3, u = gu & 7, half = tid >> 5;

    const float* wsrc = (g == 0) ? wf : (g == 1) ? wi1 : (g == 2) ? wi2 : wo;
    float wreg[28];
    #pragma unroll
    for (int j = 0; j < 28; ++j) wreg[j] = wsrc[(half * 28 + j) * 8 + u];
    float bias = ((g == 0) ? bfv : (g == 1) ? bi1 : (g == 2) ? bi2 : bov)[u];

    if (tid < 8) {
        float r = rsqrtf(v2[tid] + EPSV);
        sS[tid] = r * g2[tid] * w_out[tid];
        sZ[48 + tid] = 0.f;
    }
    if (tid == 0) {
        float k = b_out[0];
        for (int uu = 0; uu < 8; ++uu) {
            float r = rsqrtf(v2[uu] + EPSV);
            k += (b2v[uu] - m2[uu] * r * g2[uu]) * w_out[uu];
        }
        sKs = k;
    }

    float c = 0.f;
    const float* fb = feats + (size_t)b * T_ * 48;

    for (int t = 0; t < T_; ++t) {
        if (tid < 48) sZ[tid] = fb[t * 48 + tid];
        __syncthreads();

        float a = 0.f;
        #pragma unroll
        for (int j = 0; j < 28; ++j) a += sZ[half * 28 + j] * wreg[j];
        a += __shfl_xor(a, 32);
        a += bias;
        float v;
        if (g == 2) { float e = __expf(2.f * a); v = 1.f - 2.f / (e + 1.f); }
        else        { v = 1.f / (1.f + __expf(-a)); }
        if (tid < 32) sG[gu] = v;
        __syncthreads();

        if (tid < 8) {
            c = sG[tid] * c + sG[8 + tid] * sG[16 + tid];
            float e = __expf(2.f * c);
            float h = sG[24 + tid] * (1.f - 2.f / (e + 1.f));
            sZ[48 + tid] = h;
            float contrib = h * sS[tid];
            contrib += __shfl_xor(contrib, 1);
            contrib += __shfl_xor(contrib, 2);
            contrib += __shfl_xor(contrib, 4);
            if (tid == 0) out[b * T_ + t] = contrib + sKs;
        }
        __syncthreads();
    }
}

// ---------------------------------------------------------------------------
extern "C" void kernel_launch(void* const* d_in, const int* in_sizes, int n_in,
                              void* d_out, int out_size, void* d_ws, size_t ws_size,
                              hipStream_t stream)
{
    const float* x    = (const float*)d_in[0];
    const float* w1   = (const float*)d_in[1];
    const float* b1   = (const float*)d_in[2];
    const float* w2   = (const float*)d_in[3];
    const float* b2   = (const float*)d_in[4];
    const float* w3   = (const float*)d_in[5];
    const float* b3   = (const float*)d_in[6];
    const float* bn1g = (const float*)d_in[7];
    const float* bn1b = (const float*)d_in[8];
    const float* bn1m = (const float*)d_in[9];
    const float* bn1v = (const float*)d_in[10];
    const float* wf   = (const float*)d_in[11];
    const float* bf   = (const float*)d_in[12];
    const float* wi1  = (const float*)d_in[13];
    const float* bi1  = (const float*)d_in[14];
    const float* wi2  = (const float*)d_in[15];
    const float* bi2  = (const float*)d_in[16];
    const float* wo   = (const float*)d_in[17];
    const float* bo   = (const float*)d_in[18];
    const float* bn2g = (const float*)d_in[19];
    const float* bn2b = (const float*)d_in[20];
    const float* bn2m = (const float*)d_in[21];
    const float* bn2v = (const float*)d_in[22];
    const float* wout = (const float*)d_in[23];
    const float* bout = (const float*)d_in[24];

    unsigned short* wpack = (unsigned short*)d_ws;            // 2*43008 B
    float* feats = (float*)((char*)d_ws + 2 * WPACK);         // 1024*48 fp32
    const size_t need = 2 * WPACK + (size_t)NFRM * 48 * 4;
    if (ws_size < need) return;

    pack_weights<<<168, 256, 0, stream>>>(w2, w3, wpack);
    fused_cnn<<<NFRM, 1024, 0, stream>>>(x, w1, b1, b2, b3, wpack, feats,
                                         bn1g, bn1b, bn1m, bn1v);
    lstm_kernel<<<B_, 64, 0, stream>>>(feats, wf, bf, wi1, bi1, wi2, bi2, wo, bo,
                                       bn2g, bn2b, bn2m, bn2v, wout, bout,
                                       (float*)d_out);
}